// Round 2
// baseline (134.595 us; speedup 1.0000x reference)
//
#include <hip/hip_runtime.h>
#include <math.h>
#include <float.h>

// Kernel A: start[d] = first index i with seg[i] >= d (seg is sorted).
// start has D+1 entries; start[D] = N.
__global__ void start_kernel(const int* __restrict__ seg,
                             int* __restrict__ start, int N, int D) {
    int d = blockIdx.x * blockDim.x + threadIdx.x;
    if (d > D) return;
    int lo = 0, hi = N;
    while (lo < hi) {
        int mid = (lo + hi) >> 1;
        if (seg[mid] < d) lo = mid + 1; else hi = mid;
    }
    start[d] = lo;
}

// Kernel B: fully fused per-doc attention-softmax-weighted-sum.
// One block (256 thr) per doc. Online softmax: for each row, block computes
// score = feats[i,:].W + b, then rescales the running accumulator:
//   mnew = max(m, score); scale = exp(m-mnew); p = exp(score-mnew)
//   l = l*scale + p; acc = acc*scale + p*logits[i,:]
// Final: out = acc/l + (mask-1)*1e10. Empty docs write just the mask offset.
__global__ __launch_bounds__(256) void fused_kernel(
    const float* __restrict__ feats,
    const float* __restrict__ Wv,
    const float* __restrict__ bv,
    const float* __restrict__ logits,
    const int* __restrict__ start,
    const float* __restrict__ mask,
    float* __restrict__ out,
    int H, int C) {

    const int d = blockIdx.x;
    const int t = threadIdx.x;
    const int lane = t & 63;
    const int wave = t >> 6;
    const int s = start[d];
    const int e = start[d + 1];
    const int nvh = H >> 2;     // 256 for H=1024  (== blockDim fast path)
    const int nvc = C >> 2;     // 250 for C=1000

    __shared__ float red[4];
    __shared__ float sbcast;

    // Each thread permanently owns W[4t..4t+3] in registers.
    const float4* w4 = reinterpret_cast<const float4*>(Wv);
    float4 wreg = make_float4(0.f, 0.f, 0.f, 0.f);
    if (t < nvh) wreg = w4[t];
    const float bias = bv[0];

    float4 acc = make_float4(0.f, 0.f, 0.f, 0.f);
    float m = -FLT_MAX;
    float l = 0.f;

    for (int i = s; i < e; ++i) {
        // --- block-cooperative dot(feats[i,:], W) ---
        const float4* f4 = reinterpret_cast<const float4*>(feats + (size_t)i * H);
        float partial = 0.f;
        if (t < nvh) {
            float4 a = f4[t];
            partial = a.x * wreg.x + a.y * wreg.y + a.z * wreg.z + a.w * wreg.w;
        }
        for (int p = t + 256; p < nvh; p += 256) {   // dead for H=1024
            float4 a = f4[p], w = w4[p];
            partial += a.x * w.x + a.y * w.y + a.z * w.z + a.w * w.w;
        }
        #pragma unroll
        for (int off = 32; off > 0; off >>= 1)
            partial += __shfl_down(partial, off, 64);
        if (lane == 0) red[wave] = partial;
        __syncthreads();
        if (t == 0) sbcast = red[0] + red[1] + red[2] + red[3] + bias;
        __syncthreads();
        const float score = sbcast;

        // --- online softmax update + weighted accumulate ---
        const float mnew  = fmaxf(m, score);
        const float scale = __expf(m - mnew);   // first iter: exp(-huge) = 0
        const float p     = __expf(score - mnew);
        l = l * scale + p;
        m = mnew;
        if (t < nvc) {
            float4 v = reinterpret_cast<const float4*>(logits)[(size_t)i * nvc + t];
            acc.x = acc.x * scale + p * v.x;
            acc.y = acc.y * scale + p * v.y;
            acc.z = acc.z * scale + p * v.z;
            acc.w = acc.w * scale + p * v.w;
        }
        __syncthreads();   // red[] reused next iteration
    }

    if (t < nvc) {
        const float invl = (e > s) ? (1.0f / l) : 0.f;  // empty doc -> 0 + offset
        float4 mm = reinterpret_cast<const float4*>(mask)[t];
        float4 o;
        o.x = acc.x * invl + (mm.x - 1.f) * 1e10f;
        o.y = acc.y * invl + (mm.y - 1.f) * 1e10f;
        o.z = acc.z * invl + (mm.z - 1.f) * 1e10f;
        o.w = acc.w * invl + (mm.w - 1.f) * 1e10f;
        reinterpret_cast<float4*>(out)[(size_t)d * nvc + t] = o;
    }
}

extern "C" void kernel_launch(void* const* d_in, const int* in_sizes, int n_in,
                              void* d_out, int out_size, void* d_ws, size_t ws_size,
                              hipStream_t stream) {
    const float* seq_feats  = (const float*)d_in[0];
    const float* seq_logits = (const float*)d_in[1];
    const float* W_attn     = (const float*)d_in[2];
    const float* b_attn     = (const float*)d_in[3];
    const float* mask       = (const float*)d_in[4];
    const int*   seg        = (const int*)d_in[5];

    int H = in_sizes[2];          // 1024
    int C = in_sizes[4];          // 1000
    int N = in_sizes[5];          // 65536
    int D = out_size / C;         // 8192

    int* start = (int*)d_ws;      // D+1 ints

    start_kernel<<<(D + 1 + 255) / 256, 256, 0, stream>>>(seg, start, N, D);
    fused_kernel<<<D, 256, 0, stream>>>(seq_feats, W_attn, b_attn, seq_logits,
                                        start, mask, (float*)d_out, H, C);
}

// Round 3
// 125.333 us; speedup vs baseline: 1.0739x; 1.0739x over previous
//
#include <hip/hip_runtime.h>
#include <math.h>
#include <float.h>

// Kernel A: start[d] = first index i with seg[i] >= d (seg is sorted).
// start has D+1 entries; start[D] = N.
__global__ void start_kernel(const int* __restrict__ seg,
                             int* __restrict__ start, int N, int D) {
    int d = blockIdx.x * blockDim.x + threadIdx.x;
    if (d > D) return;
    int lo = 0, hi = N;
    while (lo < hi) {
        int mid = (lo + hi) >> 1;
        if (seg[mid] < d) lo = mid + 1; else hi = mid;
    }
    start[d] = lo;
}

#define SMAX 128  // rows per softmax chunk (docs avg ~8 rows; >128 handled by online rescale)

// Kernel B: fused per-doc attention + softmax + weighted sum, chunked phases:
//  P1: each wave computes scores of rows cs+wave, cs+wave+4, ... (no barriers)
//  P2: one barrier; block-redundant max/denominator; p_j -> LDS
//  P3: no barriers; each thread accumulates its float4 column over all rows (ILP)
__global__ __launch_bounds__(256) void fused_kernel(
    const float* __restrict__ feats,
    const float* __restrict__ Wv,
    const float* __restrict__ bv,
    const float* __restrict__ logits,
    const int* __restrict__ start,
    const float* __restrict__ mask,
    float* __restrict__ out,
    int H, int C) {

    const int d = blockIdx.x;
    const int t = threadIdx.x;
    const int lane = t & 63;
    const int wave = t >> 6;
    const int s = start[d];
    const int e = start[d + 1];
    const int nvh = H >> 2;   // 256 for H=1024
    const int nvc = C >> 2;   // 250 for C=1000

    __shared__ float sc[SMAX];   // raw scores of current chunk
    __shared__ float sp[SMAX];   // exp(score - m) of current chunk

    const float4* w4 = reinterpret_cast<const float4*>(Wv);
    const float bias = bv[0];

    // Hoist W into registers: lane owns w4[lane], w4[lane+64], ... (H<=1024 fast path)
    float4 wr[4];
    #pragma unroll
    for (int k = 0; k < 4; ++k) {
        int idx = lane + 64 * k;
        wr[k] = (idx < nvh) ? w4[idx] : make_float4(0.f, 0.f, 0.f, 0.f);
    }

    float4 acc = make_float4(0.f, 0.f, 0.f, 0.f);
    float m = -FLT_MAX;
    float l = 0.f;

    for (int cs = s; cs < e; cs += SMAX) {
        const int ce = min(cs + SMAX, e);
        const int len = ce - cs;

        // --- Phase 1: per-wave row scores ---
        for (int i = cs + wave; i < ce; i += 4) {
            const float4* f4 = reinterpret_cast<const float4*>(feats + (size_t)i * H);
            float partial = 0.f;
            #pragma unroll
            for (int k = 0; k < 4; ++k) {
                int idx = lane + 64 * k;
                if (idx < nvh) {
                    float4 a = f4[idx];
                    partial += a.x * wr[k].x + a.y * wr[k].y
                             + a.z * wr[k].z + a.w * wr[k].w;
                }
            }
            for (int idx = lane + 256; idx < nvh; idx += 64) {  // dead for H<=1024
                float4 a = f4[idx], w = w4[idx];
                partial += a.x * w.x + a.y * w.y + a.z * w.z + a.w * w.w;
            }
            #pragma unroll
            for (int off = 32; off > 0; off >>= 1)
                partial += __shfl_down(partial, off, 64);
            if (lane == 0) sc[i - cs] = partial + bias;
        }
        __syncthreads();

        // --- Phase 2: chunk max / exp / denom (block-redundant over <=len LDS reads) ---
        float cm = -FLT_MAX;
        for (int j = 0; j < len; ++j) cm = fmaxf(cm, sc[j]);
        const float mnew  = fmaxf(m, cm);
        const float scale = __expf(m - mnew);   // first chunk: exp(-huge) = 0
        if (t < len) sp[t] = __expf(sc[t] - mnew);
        __syncthreads();
        float csum = 0.f;
        for (int j = 0; j < len; ++j) csum += sp[j];
        l = l * scale + csum;
        m = mnew;

        // --- Phase 3: column accumulate, no barriers, loads pipeline across rows ---
        if (t < nvc) {
            acc.x *= scale; acc.y *= scale; acc.z *= scale; acc.w *= scale;
            for (int j = 0; j < len; ++j) {
                const float p = sp[j];
                float4 v = reinterpret_cast<const float4*>(logits)[(size_t)(cs + j) * nvc + t];
                acc.x += p * v.x; acc.y += p * v.y;
                acc.z += p * v.z; acc.w += p * v.w;
            }
        }
        if (ce < e) __syncthreads();   // sc/sp reused by next chunk
    }

    if (t < nvc) {
        const float invl = (e > s) ? (1.0f / l) : 0.f;  // empty doc -> just mask offset
        float4 mm = reinterpret_cast<const float4*>(mask)[t];
        float4 o;
        o.x = acc.x * invl + (mm.x - 1.f) * 1e10f;
        o.y = acc.y * invl + (mm.y - 1.f) * 1e10f;
        o.z = acc.z * invl + (mm.z - 1.f) * 1e10f;
        o.w = acc.w * invl + (mm.w - 1.f) * 1e10f;
        reinterpret_cast<float4*>(out)[(size_t)d * nvc + t] = o;
    }
}

extern "C" void kernel_launch(void* const* d_in, const int* in_sizes, int n_in,
                              void* d_out, int out_size, void* d_ws, size_t ws_size,
                              hipStream_t stream) {
    const float* seq_feats  = (const float*)d_in[0];
    const float* seq_logits = (const float*)d_in[1];
    const float* W_attn     = (const float*)d_in[2];
    const float* b_attn     = (const float*)d_in[3];
    const float* mask       = (const float*)d_in[4];
    const int*   seg        = (const int*)d_in[5];

    int H = in_sizes[2];          // 1024
    int C = in_sizes[4];          // 1000
    int N = in_sizes[5];          // 65536
    int D = out_size / C;         // 8192

    int* start = (int*)d_ws;      // D+1 ints

    start_kernel<<<(D + 1 + 255) / 256, 256, 0, stream>>>(seg, start, N, D);
    fused_kernel<<<D, 256, 0, stream>>>(seq_feats, W_attn, b_attn, seq_logits,
                                        start, mask, (float*)d_out, H, C);
}